// Round 2
// baseline (506.766 us; speedup 1.0000x reference)
//
#include <hip/hip_runtime.h>
#include <cmath>

#define H_   16
#define DU_  64
#define DP_  32
#define D_   96
#define F_   1536
#define B_   16
#define TC_  4095
#define WMAX_ 512
#define NEG_ -1000000.0f

// One block per (b,h). 512 threads = 8 waves.
// scores = (x_row . qt + c0)/sqrt(96) - pos_param*bucket + NEG  (NEG added to
//   ALL positions: the reference's double-where collapses the time mask to a
//   uniform -1e6, whose only surviving effect in fp32 is quantizing scores to
//   ulp(1e6)=0.0625 — we must replicate that quantization).
// qt = Wk^T q folds the K-projection into the query.
// out = ((sum_r attn_r x_r) Wv + bv) + residual  (V-projection folded out).
__global__ __launch_bounds__(512, 1)
void bichan_attn(const int* __restrict__ tptr,
                 const float* __restrict__ content,
                 const int* __restrict__ time_mask,   // dead in reference; unused
                 const float* __restrict__ cache,
                 const float* __restrict__ Wq_u, const float* __restrict__ bq_u,
                 const float* __restrict__ Wk_u, const float* __restrict__ bk_u,
                 const float* __restrict__ Wv_u, const float* __restrict__ bv_u,
                 const float* __restrict__ Wq_p, const float* __restrict__ bq_p,
                 const float* __restrict__ Wk_p, const float* __restrict__ bk_p,
                 const float* __restrict__ Wv_p, const float* __restrict__ bv_p,
                 const float* __restrict__ pos_param_p,
                 float* __restrict__ out)
{
    const int tid = threadIdx.x;
    const int bh  = blockIdx.x;
    const int b   = bh >> 4;
    const int h   = bh & 15;

    __shared__ __align__(16) float xcur[D_];
    __shared__ float qv[D_];
    __shared__ __align__(16) float qt[D_];
    __shared__ float c0sh;
    __shared__ float red[8];
    __shared__ float ev[WMAX_];
    __shared__ float wacc[5][D_];
    __shared__ float wsum[D_];

    const int t  = tptr[0];
    const int T  = t + 1;
    const int WL = (T < WMAX_) ? T : WMAX_;
    const int w0 = T - WL;
    const float pos_param = pos_param_p[0];

    // ---- phase 0: current-token row, q, folded qt, c0 -------------------
    if (tid < D_) xcur[tid] = content[(size_t)b * F_ + h * D_ + tid];
    __syncthreads();

    if (tid < DU_) {                     // q_u[e]
        int e = tid;
        float a = bq_u[h * DU_ + e];
        const float* W = Wq_u + (size_t)h * DU_ * DU_ + e;
        #pragma unroll 8
        for (int d = 0; d < DU_; ++d) a += xcur[d] * W[d * DU_];
        qv[e] = a;
    } else if (tid < D_) {               // q_p[e]
        int e = tid - DU_;
        float a = bq_p[h * DP_ + e];
        const float* W = Wq_p + (size_t)h * DP_ * DP_ + e;
        #pragma unroll 8
        for (int d = 0; d < DP_; ++d) a += xcur[DU_ + d] * W[d * DP_];
        qv[DU_ + e] = a;
    }
    __syncthreads();

    if (tid < DU_) {                     // qt_u[d] = sum_e Wk_u[h,d,e] q_u[e]
        int d = tid;
        const float* W = Wk_u + (size_t)h * DU_ * DU_ + (size_t)d * DU_;
        float a = 0.f;
        #pragma unroll 8
        for (int e = 0; e < DU_; ++e) a += W[e] * qv[e];
        qt[d] = a;
    } else if (tid < D_) {               // qt_p[d]
        int d = tid - DU_;
        const float* W = Wk_p + (size_t)h * DP_ * DP_ + (size_t)d * DP_;
        float a = 0.f;
        #pragma unroll 8
        for (int e = 0; e < DP_; ++e) a += W[e] * qv[DU_ + e];
        qt[DU_ + d] = a;
    } else if (tid == D_) {              // c0 = q . bk  (tiny, serial)
        float c = 0.f;
        for (int e = 0; e < DU_; ++e) c += qv[e] * bk_u[h * DU_ + e];
        for (int e = 0; e < DP_; ++e) c += qv[DU_ + e] * bk_p[h * DP_ + e];
        c0sh = c;
    }
    __syncthreads();

    // ---- phase 1: one window position per thread ------------------------
    const int r = tid;
    float s = -3.0e38f;
    if (r < WL) {
        const float* rowp = (r == WL - 1)
            ? (content + (size_t)b * F_ + h * D_)
            : (cache + ((size_t)b * TC_ + (size_t)(w0 + r)) * F_ + h * D_);
        const float4* xp  = (const float4*)rowp;
        const float4* qp4 = (const float4*)qt;
        float acc = 0.f;
        #pragma unroll
        for (int jj = 0; jj < 24; ++jj) {
            float4 x  = xp[jj];
            float4 qq = qp4[jj];   // LDS broadcast (all lanes same addr)
            acc += x.x * qq.x + x.y * qq.y + x.z * qq.z + x.w * qq.w;
        }
        s = (acc + c0sh) * 0.10206207261596577f;   // 1/sqrt(96)

        int n = WL - 1 - r;                        // distance from current
        int bkt;
        if (n < 16) bkt = n;
        else {
            double v = log((double)n / 16.0) / log(8.0) * 16.0; // fp64 = numpy
            bkt = 16 + (int)v;
            if (bkt > 31) bkt = 31;
        }
        s -= pos_param * (float)bkt;

        // Reference adds m = NEG to EVERY position (the double-where makes
        // time_mask dead). In fp32 this snaps s to multiples of 0.0625 —
        // required to match the np reference's softmax.
        s += NEG_;
    }

    // ---- phase 2: block softmax -----------------------------------------
    float m = s;
    #pragma unroll
    for (int o = 32; o > 0; o >>= 1) m = fmaxf(m, __shfl_xor(m, o, 64));
    const int wid  = tid >> 6;
    const int lane = tid & 63;
    if (lane == 0) red[wid] = m;
    __syncthreads();
    float M = red[0];
    #pragma unroll
    for (int w = 1; w < 8; ++w) M = fmaxf(M, red[w]);

    float e = (r < WL) ? __expf(s - M) : 0.f;  // s-M exact (Sterbenz near -1e6)
    ev[r] = e;
    __syncthreads();                            // red[] reuse barrier
    float l = e;
    #pragma unroll
    for (int o = 32; o > 0; o >>= 1) l += __shfl_xor(l, o, 64);
    if (lane == 0) red[wid] = l;
    __syncthreads();
    float L = red[0];
    #pragma unroll
    for (int w = 1; w < 8; ++w) L += red[w];

    // ---- phase 3: weighted cache sum, j-major coalesced re-read ---------
    const int g = tid / D_;          // 5 full groups of 96 (tid<480)
    const int j = tid - g * D_;
    if (g < 5) {
        const float* cp = cache + ((size_t)b * TC_ + (size_t)w0) * F_ + h * D_ + j;
        float acc = 0.f;
        for (int rr = g; rr < WL - 1; rr += 5)
            acc += ev[rr] * cp[(size_t)rr * F_];
        wacc[g][j] = acc;
    }
    __syncthreads();
    if (tid < D_) {
        float v = ev[WL - 1] * xcur[tid];          // current token
        #pragma unroll
        for (int g2 = 0; g2 < 5; ++g2) v += wacc[g2][tid];
        wsum[tid] = v / L;
    }
    __syncthreads();

    // ---- epilogue: V projection + bias + residual -----------------------
    if (tid < DU_) {
        int e2 = tid;
        const float* W = Wv_u + (size_t)h * DU_ * DU_ + e2;
        float a = bv_u[h * DU_ + e2];
        #pragma unroll 8
        for (int d = 0; d < DU_; ++d) a += wsum[d] * W[d * DU_];
        size_t oi = (size_t)b * F_ + h * D_ + e2;
        out[oi] = a + content[oi];
    } else if (tid < D_) {
        int e2 = tid - DU_;
        const float* W = Wv_p + (size_t)h * DP_ * DP_ + e2;
        float a = bv_p[h * DP_ + e2];
        #pragma unroll 8
        for (int d = 0; d < DP_; ++d) a += wsum[DU_ + d] * W[d * DP_];
        size_t oi = (size_t)b * F_ + h * D_ + DU_ + e2;
        out[oi] = a + content[oi];
    }
}

extern "C" void kernel_launch(void* const* d_in, const int* in_sizes, int n_in,
                              void* d_out, int out_size, void* d_ws, size_t ws_size,
                              hipStream_t stream) {
    const int*   tptr      = (const int*)d_in[0];
    const float* content   = (const float*)d_in[1];
    const int*   time_mask = (const int*)d_in[2];
    const float* cache     = (const float*)d_in[3];
    // d_in[4] = speakers (unused by reference)
    const float* Wq_u = (const float*)d_in[5];
    const float* bq_u = (const float*)d_in[6];
    const float* Wk_u = (const float*)d_in[7];
    const float* bk_u = (const float*)d_in[8];
    const float* Wv_u = (const float*)d_in[9];
    const float* bv_u = (const float*)d_in[10];
    const float* Wq_p = (const float*)d_in[11];
    const float* bq_p = (const float*)d_in[12];
    const float* Wk_p = (const float*)d_in[13];
    const float* bk_p = (const float*)d_in[14];
    const float* Wv_p = (const float*)d_in[15];
    const float* bv_p = (const float*)d_in[16];
    const float* posp = (const float*)d_in[17];
    float* outp = (float*)d_out;

    dim3 grid(B_ * H_);
    dim3 block(512);
    hipLaunchKernelGGL(bichan_attn, grid, block, 0, stream,
                       tptr, content, time_mask, cache,
                       Wq_u, bq_u, Wk_u, bk_u, Wv_u, bv_u,
                       Wq_p, bq_p, Wk_p, bk_p, Wv_p, bv_p,
                       posp, outp);
}

// Round 3
// 489.843 us; speedup vs baseline: 1.0345x; 1.0345x over previous
//
#include <hip/hip_runtime.h>
#include <cmath>

#define H_   16
#define DU_  64
#define DP_  32
#define D_   96
#define F_   1536
#define B_   16
#define TC_  4095
#define WMAX_ 512
#define NEG_ -1000000.0f

// One block per (b,h). 512 threads = 8 waves.
// scores = (x_row . qt + c0)/sqrt(96) - pos_param*bucket + NEG  (NEG added to
//   ALL positions: the reference's double-where collapses the time mask to a
//   uniform -1e6, whose surviving fp32 effect is quantizing scores to
//   ulp(1e6)=0.0625 — replicated here; gives bit-exact softmax args).
// qt = Wk^T q folds the K-projection into the query.
// out = ((sum_r attn_r x_r) Wv + bv) + residual  (V-projection folded out).
__global__ __launch_bounds__(512, 1)
void bichan_attn(const int* __restrict__ tptr,
                 const float* __restrict__ content,
                 const int* __restrict__ time_mask,   // dead in reference; unused
                 const float* __restrict__ cache,
                 const float* __restrict__ Wq_u, const float* __restrict__ bq_u,
                 const float* __restrict__ Wk_u, const float* __restrict__ bk_u,
                 const float* __restrict__ Wv_u, const float* __restrict__ bv_u,
                 const float* __restrict__ Wq_p, const float* __restrict__ bq_p,
                 const float* __restrict__ Wk_p, const float* __restrict__ bk_p,
                 const float* __restrict__ Wv_p, const float* __restrict__ bv_p,
                 const float* __restrict__ pos_param_p,
                 float* __restrict__ out)
{
    const int tid = threadIdx.x;
    const int bh  = blockIdx.x;
    const int b   = bh >> 4;
    const int h   = bh & 15;

    __shared__ __align__(16) float xcur[D_];
    __shared__ float qv[D_];
    __shared__ __align__(16) float qt[D_];
    __shared__ float c0sh;
    __shared__ float red[8];
    __shared__ float ev[WMAX_];
    __shared__ __align__(16) float wacc[20][D_];   // 7.7 KB
    __shared__ float wsum[D_];

    const int t  = tptr[0];
    const int T  = t + 1;
    const int WL = (T < WMAX_) ? T : WMAX_;
    const int w0 = T - WL;
    const float pos_param = pos_param_p[0];

    // ---- phase 0: current-token row, q, folded qt, c0 -------------------
    if (tid < D_) xcur[tid] = content[(size_t)b * F_ + h * D_ + tid];
    __syncthreads();

    if (tid < DU_) {                     // q_u[e]
        int e = tid;
        float a = bq_u[h * DU_ + e];
        const float* W = Wq_u + (size_t)h * DU_ * DU_ + e;
        #pragma unroll 8
        for (int d = 0; d < DU_; ++d) a += xcur[d] * W[d * DU_];
        qv[e] = a;
    } else if (tid < D_) {               // q_p[e]
        int e = tid - DU_;
        float a = bq_p[h * DP_ + e];
        const float* W = Wq_p + (size_t)h * DP_ * DP_ + e;
        #pragma unroll 8
        for (int d = 0; d < DP_; ++d) a += xcur[DU_ + d] * W[d * DP_];
        qv[DU_ + e] = a;
    }
    __syncthreads();

    if (tid < DU_) {                     // qt_u[d] = sum_e Wk_u[h,d,e] q_u[e]
        int d = tid;
        const float* W = Wk_u + (size_t)h * DU_ * DU_ + (size_t)d * DU_;
        float a = 0.f;
        #pragma unroll 8
        for (int e = 0; e < DU_; ++e) a += W[e] * qv[e];
        qt[d] = a;
    } else if (tid < D_) {               // qt_p[d]
        int d = tid - DU_;
        const float* W = Wk_p + (size_t)h * DP_ * DP_ + (size_t)d * DP_;
        float a = 0.f;
        #pragma unroll 8
        for (int e = 0; e < DP_; ++e) a += W[e] * qv[DU_ + e];
        qt[DU_ + d] = a;
    } else if (tid == D_) {              // c0 = q . bk  (tiny, serial)
        float c = 0.f;
        for (int e = 0; e < DU_; ++e) c += qv[e] * bk_u[h * DU_ + e];
        for (int e = 0; e < DP_; ++e) c += qv[DU_ + e] * bk_p[h * DP_ + e];
        c0sh = c;
    }
    __syncthreads();

    // ---- phase 1: one window position per thread ------------------------
    const int r = tid;
    float s = -3.0e38f;
    if (r < WL) {
        const float* rowp = (r == WL - 1)
            ? (content + (size_t)b * F_ + h * D_)
            : (cache + ((size_t)b * TC_ + (size_t)(w0 + r)) * F_ + h * D_);
        const float4* xp  = (const float4*)rowp;
        const float4* qp4 = (const float4*)qt;
        float acc = 0.f;
        #pragma unroll
        for (int jj = 0; jj < 24; ++jj) {
            float4 x  = xp[jj];
            float4 qq = qp4[jj];   // LDS broadcast (all lanes same addr)
            acc += x.x * qq.x + x.y * qq.y + x.z * qq.z + x.w * qq.w;
        }
        s = (acc + c0sh) * 0.10206207261596577f;   // 1/sqrt(96)

        int n = WL - 1 - r;                        // distance from current
        int bkt;
        if (n < 16) bkt = n;
        else {
            double v = log((double)n / 16.0) / log(8.0) * 16.0; // fp64 = numpy
            bkt = 16 + (int)v;
            if (bkt > 31) bkt = 31;
        }
        s -= pos_param * (float)bkt;

        // Reference adds m = NEG to EVERY position (double-where makes
        // time_mask dead); fp32 snaps s to 0.0625 grid — must replicate.
        s += NEG_;
    }

    // ---- phase 2: block softmax -----------------------------------------
    float m = s;
    #pragma unroll
    for (int o = 32; o > 0; o >>= 1) m = fmaxf(m, __shfl_xor(m, o, 64));
    const int wid  = tid >> 6;
    const int lane = tid & 63;
    if (lane == 0) red[wid] = m;
    __syncthreads();
    float M = red[0];
    #pragma unroll
    for (int w = 1; w < 8; ++w) M = fmaxf(M, red[w]);

    float e = (r < WL) ? __expf(s - M) : 0.f;  // s-M exact (Sterbenz near -1e6)
    ev[r] = e;
    __syncthreads();                            // red[] reuse barrier
    float l = e;
    #pragma unroll
    for (int o = 32; o > 0; o >>= 1) l += __shfl_xor(l, o, 64);
    if (lane == 0) red[wid] = l;
    __syncthreads();
    float L = red[0];
    #pragma unroll
    for (int w = 1; w < 8; ++w) L += red[w];

    // ---- phase 3: weighted cache sum, float4 j-major re-read ------------
    // 20 groups x 24 lanes; each lane owns 4 contiguous components (16 B).
    const int g  = tid / 24;          // 0..20 (g==21 for tid>=504: idle)
    const int j4 = tid - g * 24;      // float4 index 0..23 within row
    if (g < 20) {
        const float4* cp4 = (const float4*)(cache
            + ((size_t)b * TC_ + (size_t)w0) * F_ + h * D_) + j4;
        float4 acc = make_float4(0.f, 0.f, 0.f, 0.f);
        for (int rr = g; rr < WL - 1; rr += 20) {
            float4 x = cp4[(size_t)rr * (F_ / 4)];
            float  w = ev[rr];                    // LDS broadcast in group
            acc.x += w * x.x; acc.y += w * x.y;
            acc.z += w * x.z; acc.w += w * x.w;
        }
        *(float4*)&wacc[g][4 * j4] = acc;
    }
    __syncthreads();
    if (tid < D_) {
        float v = ev[WL - 1] * xcur[tid];          // current token (exact fp32)
        #pragma unroll
        for (int g2 = 0; g2 < 20; ++g2) v += wacc[g2][tid];
        wsum[tid] = v / L;
    }
    __syncthreads();

    // ---- epilogue: V projection + bias + residual -----------------------
    if (tid < DU_) {
        int e2 = tid;
        const float* W = Wv_u + (size_t)h * DU_ * DU_ + e2;
        float a = bv_u[h * DU_ + e2];
        #pragma unroll 8
        for (int d = 0; d < DU_; ++d) a += wsum[d] * W[d * DU_];
        size_t oi = (size_t)b * F_ + h * D_ + e2;
        out[oi] = a + content[oi];
    } else if (tid < D_) {
        int e2 = tid - DU_;
        const float* W = Wv_p + (size_t)h * DP_ * DP_ + e2;
        float a = bv_p[h * DP_ + e2];
        #pragma unroll 8
        for (int d = 0; d < DP_; ++d) a += wsum[DU_ + d] * W[d * DP_];
        size_t oi = (size_t)b * F_ + h * D_ + DU_ + e2;
        out[oi] = a + content[oi];
    }
}

extern "C" void kernel_launch(void* const* d_in, const int* in_sizes, int n_in,
                              void* d_out, int out_size, void* d_ws, size_t ws_size,
                              hipStream_t stream) {
    const int*   tptr      = (const int*)d_in[0];
    const float* content   = (const float*)d_in[1];
    const int*   time_mask = (const int*)d_in[2];
    const float* cache     = (const float*)d_in[3];
    // d_in[4] = speakers (unused by reference)
    const float* Wq_u = (const float*)d_in[5];
    const float* bq_u = (const float*)d_in[6];
    const float* Wk_u = (const float*)d_in[7];
    const float* bk_u = (const float*)d_in[8];
    const float* Wv_u = (const float*)d_in[9];
    const float* bv_u = (const float*)d_in[10];
    const float* Wq_p = (const float*)d_in[11];
    const float* bq_p = (const float*)d_in[12];
    const float* Wk_p = (const float*)d_in[13];
    const float* bk_p = (const float*)d_in[14];
    const float* Wv_p = (const float*)d_in[15];
    const float* bv_p = (const float*)d_in[16];
    const float* posp = (const float*)d_in[17];
    float* outp = (float*)d_out;

    dim3 grid(B_ * H_);
    dim3 block(512);
    hipLaunchKernelGGL(bichan_attn, grid, block, 0, stream,
                       tptr, content, time_mask, cache,
                       Wq_u, bq_u, Wk_u, bk_u, Wv_u, bv_u,
                       Wq_p, bq_p, Wk_p, bk_p, Wv_p, bv_p,
                       posp, outp);
}